// Round 1
// baseline (3620.430 us; speedup 1.0000x reference)
//
#include <hip/hip_runtime.h>
#include <math.h>

// Problem constants (fixed by the reference)
#define BN   8
#define NN   1024
#define FIN  256
#define HIDN 128
#define KTOP 513          // int(1024*0.5)+1
#define NITER 20          // opt_epochs in setup_inputs
#define EPS_S 0.01f
#define INV_EPS 100.0f
#define LOG_MU (-6.9314718055994531f)   // -log(1024)
#define LOG_NU (-6.9314718055994531f)
#define LOSS_BLOCKS 2048

static __device__ __forceinline__ float wred_sum(float s) {
#pragma unroll
  for (int o = 32; o > 0; o >>= 1) s += __shfl_xor(s, o);
  return s;
}
static __device__ __forceinline__ float wred_max(float s) {
#pragma unroll
  for (int o = 32; o > 0; o >>= 1) s = fmaxf(s, __shfl_xor(s, o));
  return s;
}

// ---------------- rowsum -> d = rsqrt(max(rowsum+1,1)), rmask = rowsum>0 ----
__global__ __launch_bounds__(256) void k_rowstats(const float* __restrict__ adj,
                                                  float* __restrict__ dv,
                                                  float* __restrict__ rm) {
  int row = blockIdx.x;
  const float* a = adj + (long)row * NN;
  int t = threadIdx.x;
  float4 v = *(const float4*)(a + t * 4);
  float s = v.x + v.y + v.z + v.w;
  s = wred_sum(s);
  __shared__ float sm[4];
  if ((t & 63) == 0) sm[t >> 6] = s;
  __syncthreads();
  if (t == 0) {
    float tot = sm[0] + sm[1] + sm[2] + sm[3];
    dv[row] = rsqrtf(fmaxf(tot + 1.0f, 1.0f));
    rm[row] = tot > 0.0f ? 1.0f : 0.0f;
  }
}

// ---------------- s0 = cx @ Watt  (per-row dot, HID=128) --------------------
__global__ __launch_bounds__(256) void k_rowdot(const float* __restrict__ X,
                                                const float* __restrict__ w,
                                                float* __restrict__ out) {
  int t = threadIdx.x; int lane = t & 63; int wv = t >> 6;
  int row = blockIdx.x * 4 + wv;
  const float* xr = X + (long)row * HIDN;
  float s = xr[lane] * w[lane] + xr[lane + 64] * w[lane + 64];
  s = wred_sum(s);
  if (lane == 0) out[row] = s;
}

// ---------------- alpha = sigmoid((gcn_norm(adj) @ s0 + batt)^2) ------------
__global__ __launch_bounds__(256) void k_alpha(const float* __restrict__ adj,
                                               const float* __restrict__ dv,
                                               const float* __restrict__ s0,
                                               const float* __restrict__ batt,
                                               float* __restrict__ alpha) {
  int row = blockIdx.x; int b = row >> 10; int i = row & (NN - 1);
  const float* a = adj + (long)row * NN;
  const float* db = dv + (b << 10);
  const float* sb = s0 + (b << 10);
  int t = threadIdx.x;
  float s = 0.f;
#pragma unroll
  for (int q = 0; q < 4; ++q) {
    int j = (q << 8) + t;
    float av = a[j] + (j == i ? 1.f : 0.f);
    s += av * db[j] * sb[j];
  }
  s = wred_sum(s);
  __shared__ float sm[4];
  if ((t & 63) == 0) sm[t >> 6] = s;
  __syncthreads();
  if (t == 0) {
    float tt = db[i] * (sm[0] + sm[1] + sm[2] + sm[3]) + batt[0];
    alpha[row] = 1.f / (1.f + __expf(-tt * tt));
  }
}

// ---------------- per-batch k-th largest via bitonic sort -------------------
__global__ __launch_bounds__(512) void k_topk(const float* __restrict__ alpha,
                                              float* __restrict__ cut) {
  __shared__ float smv[NN];
  int b = blockIdx.x; int t = threadIdx.x;
  smv[t] = alpha[(b << 10) + t];
  smv[t + 512] = alpha[(b << 10) + t + 512];
  __syncthreads();
  for (int k2 = 2; k2 <= NN; k2 <<= 1) {
    for (int j2 = k2 >> 1; j2 > 0; j2 >>= 1) {
      int i = ((t / j2) * (j2 << 1)) + (t % j2);
      int ixj = i + j2;
      bool up = ((i & k2) == 0);
      float a = smv[i], c = smv[ixj];
      if ((a > c) == up) { smv[i] = c; smv[ixj] = a; }
      __syncthreads();
    }
  }
  if (t == 0) cut[b] = smv[NN - KTOP];   // ascending sort: 513th largest
}

// ---------------- S build: rmask_i d_i d_j (adj+I) * gate_j, row-L1 norm ----
__global__ __launch_bounds__(256) void k_sbuild(const float* __restrict__ adj,
                                                const float* __restrict__ dv,
                                                const float* __restrict__ rm,
                                                const float* __restrict__ alpha,
                                                const float* __restrict__ cut,
                                                float* __restrict__ S) {
  int row = blockIdx.x; int b = row >> 10; int i = row & (NN - 1);
  const float* a = adj + (long)row * NN;
  const float* db = dv + (b << 10);
  const float* al = alpha + (b << 10);
  float cb = cut[b];
  float di = dv[row] * rm[row];
  int t = threadIdx.x;
  float vals[4]; float s = 0.f;
#pragma unroll
  for (int q = 0; q < 4; ++q) {
    int j = (q << 8) + t;
    float av = a[j] + (j == i ? 1.f : 0.f);
    float gate = fmaxf(al[j] + 1e-7f - cb, 0.f);
    float vv = di * db[j] * av * gate;
    vals[q] = vv; s += fabsf(vv);
  }
  s = wred_sum(s);
  __shared__ float sm[4]; __shared__ float stot;
  if ((t & 63) == 0) sm[t >> 6] = s;
  __syncthreads();
  if (t == 0) stot = 1.f / fmaxf(sm[0] + sm[1] + sm[2] + sm[3], 1e-12f);
  __syncthreads();
  float inv = stot;
  float* Sr = S + (long)row * NN;
#pragma unroll
  for (int q = 0; q < 4; ++q) Sr[(q << 8) + t] = vals[q] * inv;
}

// ---------------- generic fp32 tiled GEMM ----------------------------------
// out[m,n] = sum_k Aeff[m,k] * Beff[k,n]
// TA: Aeff[m,k] = A[k*M + m]  (else A[m*K + k])
// TB: Beff[k,n] = B[n*K + k]  (else B[k*Nn + n])
// GCN (TA=0 only): Aeff[m,k] = d[m]*d[k]*(A[m*K+k] + (m==k))
// EPI 0: plain; 1: +bias[n], optional relu; 2: out = xx[m]+yy[n]-2*acc
template<int TA, int TB, int GCN, int EPI>
__global__ __launch_bounds__(256) void k_gemm(
    const float* __restrict__ A, const float* __restrict__ Bm, float* __restrict__ Cm,
    int M, int Nn, int K, long sA, long sB, long sC,
    const float* __restrict__ dv, const float* __restrict__ bias, int relu,
    const float* __restrict__ xx, const float* __restrict__ yy) {
  __shared__ float As[8][132];
  __shared__ float Bs[8][132];
  int b = blockIdx.z;
  A += (long)b * sA; Bm += (long)b * sB; Cm += (long)b * sC;
  const float* dvb = GCN ? (dv + (long)b * NN) : nullptr;
  const float* xxb = (EPI == 2) ? (xx + (long)b * NN) : nullptr;
  const float* yyb = (EPI == 2) ? (yy + (long)b * NN) : nullptr;
  int m0 = blockIdx.y * 128, n0 = blockIdx.x * 128;
  int tid = threadIdx.x;
  int tx = tid & 15, ty = tid >> 4;
  float acc[8][8];
#pragma unroll
  for (int i = 0; i < 8; i++)
#pragma unroll
    for (int j = 0; j < 8; j++) acc[i][j] = 0.f;

  float drow = 0.f;
  if (GCN) drow = dvb[m0 + (tid >> 1)];

  for (int k0 = 0; k0 < K; k0 += 8) {
    if (TA == 0) {
      int r = tid >> 1, c4 = (tid & 1) * 4;
      float4 av = *(const float4*)(A + (long)(m0 + r) * K + k0 + c4);
      float a4[4] = {av.x, av.y, av.z, av.w};
      if (GCN) {
#pragma unroll
        for (int q = 0; q < 4; ++q) {
          int gj = k0 + c4 + q;
          float val = a4[q] + ((m0 + r) == gj ? 1.f : 0.f);
          a4[q] = drow * dvb[gj] * val;
        }
      }
      As[c4 + 0][r] = a4[0]; As[c4 + 1][r] = a4[1];
      As[c4 + 2][r] = a4[2]; As[c4 + 3][r] = a4[3];
    } else {
      int kr = tid >> 5, c4 = (tid & 31) * 4;
      float4 av = *(const float4*)(A + (long)(k0 + kr) * M + m0 + c4);
      *(float4*)&As[kr][c4] = av;
    }
    if (TB == 0) {
      int kr = tid >> 5, c4 = (tid & 31) * 4;
      float4 bv = *(const float4*)(Bm + (long)(k0 + kr) * Nn + n0 + c4);
      *(float4*)&Bs[kr][c4] = bv;
    } else {
      int r = tid >> 1, c4 = (tid & 1) * 4;
      float4 bv = *(const float4*)(Bm + (long)(n0 + r) * K + k0 + c4);
      Bs[c4 + 0][r] = bv.x; Bs[c4 + 1][r] = bv.y;
      Bs[c4 + 2][r] = bv.z; Bs[c4 + 3][r] = bv.w;
    }
    __syncthreads();
#pragma unroll
    for (int k = 0; k < 8; ++k) {
      float av[8], bv[8];
      *(float4*)&av[0] = *(const float4*)&As[k][ty * 8];
      *(float4*)&av[4] = *(const float4*)&As[k][ty * 8 + 4];
      *(float4*)&bv[0] = *(const float4*)&Bs[k][tx * 8];
      *(float4*)&bv[4] = *(const float4*)&Bs[k][tx * 8 + 4];
#pragma unroll
      for (int i = 0; i < 8; i++)
#pragma unroll
        for (int j = 0; j < 8; j++)
          acc[i][j] = fmaf(av[i], bv[j], acc[i][j]);
    }
    __syncthreads();
  }
#pragma unroll
  for (int i = 0; i < 8; ++i) {
    int m = m0 + ty * 8 + i;
    float* crow = Cm + (long)m * Nn + n0 + tx * 8;
    float outv[8];
#pragma unroll
    for (int j = 0; j < 8; ++j) {
      float vv = acc[i][j];
      if (EPI == 1) { vv += bias[n0 + tx * 8 + j]; if (relu) vv = fmaxf(vv, 0.f); }
      if (EPI == 2) { vv = xxb[m] + yyb[n0 + tx * 8 + j] - 2.f * vv; }
      outv[j] = vv;
    }
    *(float4*)&crow[0] = *(float4*)&outv[0];
    *(float4*)&crow[4] = *(float4*)&outv[4];
  }
}

// ---------------- column mean over nodes ------------------------------------
__global__ __launch_bounds__(256) void k_colmean(const float* __restrict__ X, int Fd,
                                                 float* __restrict__ out) {
  int nb = Fd >> 6;
  int b = blockIdx.x / nb; int f0 = (blockIdx.x % nb) << 6;
  int t = threadIdx.x;
  int f = f0 + (t & 63); int rc = t >> 6;
  const float* xb = X + (long)b * NN * Fd;
  float s = 0.f;
  for (int i = rc * 256; i < rc * 256 + 256; ++i) s += xb[(long)i * Fd + f];
  __shared__ float sm[256];
  sm[t] = s; __syncthreads();
  if (t < 64) out[b * Fd + f] = (sm[t] + sm[t + 64] + sm[t + 128] + sm[t + 192]) * (1.f / NN);
}

// ---------------- squared row norms -----------------------------------------
__global__ __launch_bounds__(256) void k_sqnorm(const float* __restrict__ X, int Fd,
                                                float* __restrict__ out) {
  int t = threadIdx.x; int lane = t & 63; int wv = t >> 6;
  int row = blockIdx.x * 4 + wv;
  const float* xr = X + (long)row * Fd;
  float s = 0.f;
  for (int f = lane; f < Fd; f += 64) { float v = xr[f]; s = fmaf(v, v, s); }
  s = wred_sum(s);
  if (lane == 0) out[row] = s;
}

// ---------------- Sinkhorn row pass: u_i = eps*(log_mu - LSE_j((v_j-C_ij)/eps))
__global__ __launch_bounds__(256) void k_sink_row(const float* __restrict__ Cmat,
                                                  const float* __restrict__ vvec,
                                                  float* __restrict__ uvec) {
  int row = blockIdx.x; int b = row >> 10;
  const float* cr = Cmat + (long)row * NN;
  const float* vb = vvec + (b << 10);
  int t = threadIdx.x;
  float a[4]; float mx = -3.0e38f;
#pragma unroll
  for (int q = 0; q < 4; ++q) {
    int j = (q << 8) + t;
    a[q] = (vb[j] - cr[j]) * INV_EPS;
    mx = fmaxf(mx, a[q]);
  }
  mx = wred_max(mx);
  __shared__ float smm[4], sms[4];
  int lane = t & 63, wv = t >> 6;
  if (lane == 0) smm[wv] = mx;
  __syncthreads();
  float M2 = fmaxf(fmaxf(smm[0], smm[1]), fmaxf(smm[2], smm[3]));
  float s = 0.f;
#pragma unroll
  for (int q = 0; q < 4; ++q) s += __expf(a[q] - M2);
  s = wred_sum(s);
  if (lane == 0) sms[wv] = s;
  __syncthreads();
  if (t == 0) {
    float tot = sms[0] + sms[1] + sms[2] + sms[3];
    uvec[row] = EPS_S * (LOG_MU - (M2 + __logf(tot)));
  }
}

// ---------------- Sinkhorn col pass: v_j = eps*(log_nu - LSE_i((u_i-C_ij)/eps))
__global__ __launch_bounds__(256) void k_sink_col(const float* __restrict__ Cmat,
                                                  const float* __restrict__ uvec,
                                                  float* __restrict__ vvec) {
  int b = blockIdx.y;
  int t = threadIdx.x;
  int j = (blockIdx.x << 6) + (t & 63);
  int chunk = t >> 6;
  const float* cb = Cmat + ((long)b << 20);
  const float* ub = uvec + (b << 10);
  float mx = -3.0e38f, s = 0.f;
  int i0 = chunk << 8;
  for (int i = i0; i < i0 + 256; ++i) {
    float av = (ub[i] - cb[((long)i << 10) + j]) * INV_EPS;
    if (av > mx) { s = s * __expf(mx - av) + 1.f; mx = av; }
    else s += __expf(av - mx);
  }
  __shared__ float smm[256], sms[256];
  smm[t] = mx; sms[t] = s;
  __syncthreads();
  if (t < 64) {
    float M2 = smm[t], S2 = sms[t];
#pragma unroll
    for (int c = 1; c < 4; ++c) {
      float mm = smm[t + (c << 6)], ss = sms[t + (c << 6)];
      if (mm > M2) { S2 = S2 * __expf(M2 - mm) + ss; M2 = mm; }
      else S2 += ss * __expf(mm - M2);
    }
    vvec[(b << 10) + j] = EPS_S * (LOG_NU - (M2 + __logf(S2)));
  }
}

// ---------------- loss = sum exp((u+v-C)/eps) * C ---------------------------
__global__ __launch_bounds__(256) void k_loss(const float* __restrict__ Cmat,
                                              const float* __restrict__ u,
                                              const float* __restrict__ v,
                                              float* __restrict__ part) {
  long total = (long)BN * NN * NN;
  float acc = 0.f;
  for (long idx = (long)blockIdx.x * blockDim.x + threadIdx.x; idx < total;
       idx += (long)gridDim.x * blockDim.x) {
    int b = (int)(idx >> 20);
    int i = (int)((idx >> 10) & (NN - 1));
    int j = (int)(idx & (NN - 1));
    float Cv = Cmat[idx];
    float a = (u[(b << 10) + i] + v[(b << 10) + j] - Cv) * INV_EPS;
    acc = fmaf(__expf(a), Cv, acc);
  }
  acc = wred_sum(acc);
  __shared__ float sm[4];
  if ((threadIdx.x & 63) == 0) sm[threadIdx.x >> 6] = acc;
  __syncthreads();
  if (threadIdx.x == 0) part[blockIdx.x] = sm[0] + sm[1] + sm[2] + sm[3];
}

__global__ __launch_bounds__(256) void k_psum(const float* __restrict__ part,
                                              float* __restrict__ out) {
  float s = 0.f;
  for (int i = threadIdx.x; i < LOSS_BLOCKS; i += 256) s += part[i];
  s = wred_sum(s);
  __shared__ float sm[4];
  if ((threadIdx.x & 63) == 0) sm[threadIdx.x >> 6] = s;
  __syncthreads();
  if (threadIdx.x == 0) out[0] = sm[0] + sm[1] + sm[2] + sm[3];
}

extern "C" void kernel_launch(void* const* d_in, const int* in_sizes, int n_in,
                              void* d_out, int out_size, void* d_ws, size_t ws_size,
                              hipStream_t stream) {
  const float* x    = (const float*)d_in[0];
  const float* adj  = (const float*)d_in[1];
  const float* W1   = (const float*)d_in[3];
  const float* b1   = (const float*)d_in[4];
  const float* Watt = (const float*)d_in[5];
  const float* batt = (const float*)d_in[6];
  const float* W2   = (const float*)d_in[7];
  const float* b2   = (const float*)d_in[8];

  float* out = (float*)d_out;
  float* xs0   = out;                    // [8,128]
  float* xs1   = out + 1024;             // [8,256]
  float* oadj0 = out + 3072;             // [8,1024,1024]
  float* oadj1 = oadj0 + 8388608;
  float* oadj2 = oadj1 + 8388608;
  float* oS0   = oadj2 + 8388608;
  float* oS1   = oS0 + 8388608;
  float* oloss = oS1 + 8388608;          // [1]

  float* ws   = (float*)d_ws;
  float* wXW  = ws;                      // 2,097,152  (x@W1 / emb2@W2)
  float* wCXA = wXW + 2097152;           // 1,048,576  (x1 then emb2)
  float* wCXB = wCXA + 1048576;          // 1,048,576  (emb1)
  float* wTMP = wCXB + 1048576;          // 8,388,608  (S^T adj, then Sinkhorn C)
  float* wX2  = wTMP + 8388608;          // 2,097,152  (x2)
  float* smb  = wX2 + 2097152;
  float* d0 = smb;            float* rm0 = smb + 8192;
  float* d1 = smb + 16384;    float* rm1 = smb + 24576;
  float* d2 = smb + 32768;    float* rm2 = smb + 40960;
  float* s0v = smb + 49152;   float* alp = smb + 57344;
  float* xxv = smb + 65536;   float* yyv = smb + 73728;
  float* uv  = smb + 81920;   float* vv  = smb + 90112;   // contiguous (memset both)
  float* cutv = smb + 98304;  // 8
  float* part = smb + 98368;  // 2048

  // new_adjs[0] = adj (straight copy)
  hipMemcpyAsync(oadj0, adj, (size_t)8388608 * 4, hipMemcpyDeviceToDevice, stream);

  // ---- first GCN layer: x1 = relu(norm(adj) @ (x@W1) + b1) ----
  k_rowstats<<<8192, 256, 0, stream>>>(adj, d0, rm0);
  k_gemm<0,0,0,0><<<dim3(1, 64, 1), 256, 0, stream>>>(x, W1, wXW, 8192, HIDN, FIN,
      0L, 0L, 0L, nullptr, nullptr, 0, nullptr, nullptr);
  k_gemm<0,0,1,1><<<dim3(1, 8, 8), 256, 0, stream>>>(adj, wXW, wCXA, 1024, HIDN, 1024,
      1048576L, 131072L, 131072L, d0, b1, 1, nullptr, nullptr);
  k_colmean<<<16, 256, 0, stream>>>(wCXA, HIDN, xs0);

  // ---- coarsen layers ----
  auto coarsen = [&](const float* curadj, const float* dcur, const float* rmcur,
                     const float* cx, float* Sout, float* embout, float* adjout) {
    k_rowdot<<<2048, 256, 0, stream>>>(cx, Watt, s0v);
    k_alpha<<<8192, 256, 0, stream>>>(curadj, dcur, s0v, batt, alp);
    k_topk<<<8, 512, 0, stream>>>(alp, cutv);
    k_sbuild<<<8192, 256, 0, stream>>>(curadj, dcur, rmcur, alp, cutv, Sout);
    // emb = S^T cx
    k_gemm<1,0,0,0><<<dim3(1, 8, 8), 256, 0, stream>>>(Sout, cx, embout, 1024, HIDN, 1024,
        1048576L, 131072L, 131072L, nullptr, nullptr, 0, nullptr, nullptr);
    // tmp = S^T adj
    k_gemm<1,0,0,0><<<dim3(8, 8, 8), 256, 0, stream>>>(Sout, curadj, wTMP, 1024, 1024, 1024,
        1048576L, 1048576L, 1048576L, nullptr, nullptr, 0, nullptr, nullptr);
    // new_adj = tmp @ S
    k_gemm<0,0,0,0><<<dim3(8, 8, 8), 256, 0, stream>>>(wTMP, Sout, adjout, 1024, 1024, 1024,
        1048576L, 1048576L, 1048576L, nullptr, nullptr, 0, nullptr, nullptr);
  };

  coarsen(adj, d0, rm0, wCXA, oS0, wCXB, oadj1);
  k_rowstats<<<8192, 256, 0, stream>>>(oadj1, d1, rm1);
  coarsen(oadj1, d1, rm1, wCXB, oS1, wCXA, oadj2);

  // ---- final GCN: x2 = norm(new_adj2) @ (emb2@W2) + b2 ----
  k_rowstats<<<8192, 256, 0, stream>>>(oadj2, d2, rm2);
  k_gemm<0,0,0,0><<<dim3(2, 64, 1), 256, 0, stream>>>(wCXA, W2, wXW, 8192, FIN, HIDN,
      0L, 0L, 0L, nullptr, nullptr, 0, nullptr, nullptr);
  k_gemm<0,0,1,1><<<dim3(2, 8, 8), 256, 0, stream>>>(oadj2, wXW, wX2, 1024, FIN, 1024,
      1048576L, 262144L, 262144L, d2, b2, 0, nullptr, nullptr);
  k_colmean<<<32, 256, 0, stream>>>(wX2, FIN, xs1);

  // ---- Sinkhorn: C = |x|^2 + |y|^2 - 2 x y^T, 20 iterations, loss ----
  k_sqnorm<<<2048, 256, 0, stream>>>(x, FIN, xxv);
  k_sqnorm<<<2048, 256, 0, stream>>>(wX2, FIN, yyv);
  k_gemm<0,1,0,2><<<dim3(8, 8, 8), 256, 0, stream>>>(x, wX2, wTMP, 1024, 1024, FIN,
      262144L, 262144L, 1048576L, nullptr, nullptr, 0, xxv, yyv);
  hipMemsetAsync(uv, 0, (size_t)2 * 8192 * 4, stream);
  for (int it = 0; it < NITER; ++it) {
    k_sink_row<<<8192, 256, 0, stream>>>(wTMP, vv, uv);
    k_sink_col<<<dim3(16, 8), 256, 0, stream>>>(wTMP, uv, vv);
  }
  k_loss<<<LOSS_BLOCKS, 256, 0, stream>>>(wTMP, uv, vv, part);
  k_psum<<<1, 256, 0, stream>>>(part, oloss);
}

// Round 2
// 2647.099 us; speedup vs baseline: 1.3677x; 1.3677x over previous
//
#include <hip/hip_runtime.h>
#include <math.h>

// Problem constants (fixed by the reference)
#define BN   8
#define NN   1024
#define FIN  256
#define HIDN 128
#define KTOP 513          // int(1024*0.5)+1
#define NITER 20          // opt_epochs in setup_inputs
#define EPS_S 0.01f
#define INV_EPS 100.0f
#define LOG_MU (-6.9314718055994531f)   // -log(1024)
#define LOG_NU (-6.9314718055994531f)
#define LOSS_BLOCKS 2048

typedef __attribute__((ext_vector_type(8))) short bfrag8;   // 8 bf16 (4 VGPR)
typedef __attribute__((ext_vector_type(4))) float facc4;    // MFMA accumulator

#define GLOAD16(g, l) __builtin_amdgcn_global_load_lds( \
    (const __attribute__((address_space(1))) unsigned int*)(g), \
    (__attribute__((address_space(3))) unsigned int*)(l), 16, 0, 0)

static __device__ __forceinline__ float wred_sum(float s) {
#pragma unroll
  for (int o = 32; o > 0; o >>= 1) s += __shfl_xor(s, o);
  return s;
}
static __device__ __forceinline__ float wred_max(float s) {
#pragma unroll
  for (int o = 32; o > 0; o >>= 1) s = fmaxf(s, __shfl_xor(s, o));
  return s;
}
static __device__ __forceinline__ unsigned short f2b(float f) {
  unsigned int u = __float_as_uint(f);
  u += 0x7fff + ((u >> 16) & 1);      // RNE
  return (unsigned short)(u >> 16);
}

// ---------------- rowsum -> d = rsqrt(max(rowsum+1,1)), rmask = rowsum>0 ----
__global__ __launch_bounds__(256) void k_rowstats(const float* __restrict__ adj,
                                                  float* __restrict__ dv,
                                                  float* __restrict__ rm) {
  int row = blockIdx.x;
  const float* a = adj + (long)row * NN;
  int t = threadIdx.x;
  float4 v = *(const float4*)(a + t * 4);
  float s = v.x + v.y + v.z + v.w;
  s = wred_sum(s);
  __shared__ float sm[4];
  if ((t & 63) == 0) sm[t >> 6] = s;
  __syncthreads();
  if (t == 0) {
    float tot = sm[0] + sm[1] + sm[2] + sm[3];
    dv[row] = rsqrtf(fmaxf(tot + 1.0f, 1.0f));
    rm[row] = tot > 0.0f ? 1.0f : 0.0f;
  }
}

// ---------------- fp32 -> bf16 elementwise ----------------------------------
__global__ __launch_bounds__(256) void k_f2b(const float* __restrict__ X,
                                             unsigned short* __restrict__ Y) {
  long i = ((long)blockIdx.x * 256 + threadIdx.x) * 4;
  float4 v = *(const float4*)(X + i);
  Y[i] = f2b(v.x); Y[i + 1] = f2b(v.y); Y[i + 2] = f2b(v.z); Y[i + 3] = f2b(v.w);
}

// ---------------- fp32 [R][C] -> bf16 [C][R] transpose ----------------------
__global__ __launch_bounds__(256) void k_transp(const float* __restrict__ X,
                                                unsigned short* __restrict__ Xt,
                                                int R, int C) {
  __shared__ float tile[64][65];
  long bb = blockIdx.z;
  const float* Xb = X + bb * (long)R * C;
  unsigned short* Xtb = Xt + bb * (long)R * C;
  int r0 = blockIdx.y * 64, c0 = blockIdx.x * 64;
  int t = threadIdx.x;
  int tr = t >> 4, tc4 = (t & 15) * 4;
#pragma unroll
  for (int p = 0; p < 4; ++p) {
    float4 v = *(const float4*)(Xb + (long)(r0 + tr + p * 16) * C + c0 + tc4);
    tile[tr + p * 16][tc4 + 0] = v.x; tile[tr + p * 16][tc4 + 1] = v.y;
    tile[tr + p * 16][tc4 + 2] = v.z; tile[tr + p * 16][tc4 + 3] = v.w;
  }
  __syncthreads();
  int jj = t >> 2, i0 = (t & 3) * 16;
  unsigned short* orow = Xtb + (long)(c0 + jj) * R + r0 + i0;
#pragma unroll
  for (int q = 0; q < 16; ++q) orow[q] = f2b(tile[i0 + q][jj]);
}

// ---------------- bf16 NT MFMA GEMM: C[m,n] = sum_k A[m,k]*B[n,k] -----------
// A [M][K] row-major bf16 (ldA), B [N][K] row-major bf16 (ldB).
// 128x128 tile, BK=32, 4 waves (64x64 each), 16x16x32 MFMA, fp32 accum.
// WF32: write float C; WBF: write bf16 C.
template<int WF32, int WBF>
__global__ __launch_bounds__(256) void k_mfma_nt(
    const unsigned short* __restrict__ A, const unsigned short* __restrict__ B,
    float* __restrict__ Cf, unsigned short* __restrict__ Cb,
    int K, int ldA, int ldB, int ldC, long sA, long sB, long sC) {
  __shared__ unsigned short As[128 * 32];
  __shared__ unsigned short Bs[128 * 32];
  int bz = blockIdx.z;
  A += bz * sA; B += bz * sB;
  int m0 = blockIdx.y * 128, n0 = blockIdx.x * 128;
  int tid = threadIdx.x, lane = tid & 63, w = tid >> 6;
  int wr = w >> 1, wc = w & 1;
  facc4 acc[4][4];
#pragma unroll
  for (int i = 0; i < 4; ++i)
#pragma unroll
    for (int j = 0; j < 4; ++j)
#pragma unroll
      for (int q = 0; q < 4; ++q) acc[i][j][q] = 0.f;

  int rA0 = w * 16 + (lane >> 2);   // staging row within 64-row half
  int kslot = lane & 3;             // 16B slot within 64B row

  for (int k0 = 0; k0 < K; k0 += 32) {
#pragma unroll
    for (int i = 0; i < 2; ++i) {
      int row = i * 64 + rA0;
      int ks = (kslot ^ (row & 3)) << 3;   // pre-swizzled global source
      GLOAD16(A + (long)(m0 + row) * ldA + k0 + ks, As + (i * 64 + w * 16) * 32);
      GLOAD16(B + (long)(n0 + row) * ldB + k0 + ks, Bs + (i * 64 + w * 16) * 32);
    }
    __syncthreads();   // compiler drains vmcnt before s_barrier
    bfrag8 af[4], bfr[4];
#pragma unroll
    for (int mi = 0; mi < 4; ++mi) {
      int row = wr * 64 + mi * 16 + (lane & 15);
      int sl = (((lane >> 4) ^ (row & 3)) << 3);   // swizzled read
      af[mi] = *(const bfrag8*)(As + row * 32 + sl);
    }
#pragma unroll
    for (int ni = 0; ni < 4; ++ni) {
      int row = wc * 64 + ni * 16 + (lane & 15);
      int sl = (((lane >> 4) ^ (row & 3)) << 3);
      bfr[ni] = *(const bfrag8*)(Bs + row * 32 + sl);
    }
#pragma unroll
    for (int mi = 0; mi < 4; ++mi)
#pragma unroll
      for (int ni = 0; ni < 4; ++ni)
        acc[mi][ni] = __builtin_amdgcn_mfma_f32_16x16x32_bf16(
            af[mi], bfr[ni], acc[mi][ni], 0, 0, 0);
    __syncthreads();
  }
  if (WF32) Cf += bz * sC;
  if (WBF) Cb += bz * sC;
#pragma unroll
  for (int mi = 0; mi < 4; ++mi) {
    int rowb = m0 + wr * 64 + mi * 16 + ((lane >> 4) << 2);
#pragma unroll
    for (int ni = 0; ni < 4; ++ni) {
      int col = n0 + wc * 64 + ni * 16 + (lane & 15);
#pragma unroll
      for (int q = 0; q < 4; ++q) {
        long off = (long)(rowb + q) * ldC + col;
        float v = acc[mi][ni][q];
        if (WF32) Cf[off] = v;
        if (WBF) Cb[off] = f2b(v);
      }
    }
  }
}

// ---------------- s0 = cx @ Watt  (per-row dot, HID=128) --------------------
__global__ __launch_bounds__(256) void k_rowdot(const float* __restrict__ X,
                                                const float* __restrict__ w,
                                                float* __restrict__ out) {
  int t = threadIdx.x; int lane = t & 63; int wv = t >> 6;
  int row = blockIdx.x * 4 + wv;
  const float* xr = X + (long)row * HIDN;
  float s = xr[lane] * w[lane] + xr[lane + 64] * w[lane + 64];
  s = wred_sum(s);
  if (lane == 0) out[row] = s;
}

// ---------------- alpha = sigmoid((gcn_norm(adj) @ s0 + batt)^2) ------------
__global__ __launch_bounds__(256) void k_alpha(const float* __restrict__ adj,
                                               const float* __restrict__ dv,
                                               const float* __restrict__ s0,
                                               const float* __restrict__ batt,
                                               float* __restrict__ alpha) {
  int row = blockIdx.x; int b = row >> 10; int i = row & (NN - 1);
  const float* a = adj + (long)row * NN;
  const float* db = dv + (b << 10);
  const float* sb = s0 + (b << 10);
  int t = threadIdx.x;
  float s = 0.f;
#pragma unroll
  for (int q = 0; q < 4; ++q) {
    int j = (q << 8) + t;
    float av = a[j] + (j == i ? 1.f : 0.f);
    s += av * db[j] * sb[j];
  }
  s = wred_sum(s);
  __shared__ float sm[4];
  if ((t & 63) == 0) sm[t >> 6] = s;
  __syncthreads();
  if (t == 0) {
    float tt = db[i] * (sm[0] + sm[1] + sm[2] + sm[3]) + batt[0];
    alpha[row] = 1.f / (1.f + __expf(-tt * tt));
  }
}

// ---------------- per-batch k-th largest via bitonic sort -------------------
__global__ __launch_bounds__(512) void k_topk(const float* __restrict__ alpha,
                                              float* __restrict__ cut) {
  __shared__ float smv[NN];
  int b = blockIdx.x; int t = threadIdx.x;
  smv[t] = alpha[(b << 10) + t];
  smv[t + 512] = alpha[(b << 10) + t + 512];
  __syncthreads();
  for (int k2 = 2; k2 <= NN; k2 <<= 1) {
    for (int j2 = k2 >> 1; j2 > 0; j2 >>= 1) {
      int i = ((t / j2) * (j2 << 1)) + (t % j2);
      int ixj = i + j2;
      bool up = ((i & k2) == 0);
      float a = smv[i], c = smv[ixj];
      if ((a > c) == up) { smv[i] = c; smv[ixj] = a; }
      __syncthreads();
    }
  }
  if (t == 0) cut[b] = smv[NN - KTOP];   // ascending sort: 513th largest
}

// ---------------- S build: rmask_i d_i d_j (adj+I) * gate_j, row-L1 norm ----
__global__ __launch_bounds__(256) void k_sbuild(const float* __restrict__ adj,
                                                const float* __restrict__ dv,
                                                const float* __restrict__ rm,
                                                const float* __restrict__ alpha,
                                                const float* __restrict__ cut,
                                                float* __restrict__ S) {
  int row = blockIdx.x; int b = row >> 10; int i = row & (NN - 1);
  const float* a = adj + (long)row * NN;
  const float* db = dv + (b << 10);
  const float* al = alpha + (b << 10);
  float cb = cut[b];
  float di = dv[row] * rm[row];
  int t = threadIdx.x;
  float vals[4]; float s = 0.f;
#pragma unroll
  for (int q = 0; q < 4; ++q) {
    int j = (q << 8) + t;
    float av = a[j] + (j == i ? 1.f : 0.f);
    float gate = fmaxf(al[j] + 1e-7f - cb, 0.f);
    float vv = di * db[j] * av * gate;
    vals[q] = vv; s += fabsf(vv);
  }
  s = wred_sum(s);
  __shared__ float sm[4]; __shared__ float stot;
  if ((t & 63) == 0) sm[t >> 6] = s;
  __syncthreads();
  if (t == 0) stot = 1.f / fmaxf(sm[0] + sm[1] + sm[2] + sm[3], 1e-12f);
  __syncthreads();
  float inv = stot;
  float* Sr = S + (long)row * NN;
#pragma unroll
  for (int q = 0; q < 4; ++q) Sr[(q << 8) + t] = vals[q] * inv;
}

// ---------------- generic fp32 tiled GEMM (kept for fp32-critical paths) ----
template<int TA, int TB, int GCN, int EPI>
__global__ __launch_bounds__(256) void k_gemm(
    const float* __restrict__ A, const float* __restrict__ Bm, float* __restrict__ Cm,
    int M, int Nn, int K, long sA, long sB, long sC,
    const float* __restrict__ dv, const float* __restrict__ bias, int relu,
    const float* __restrict__ xx, const float* __restrict__ yy) {
  __shared__ float As[8][132];
  __shared__ float Bs[8][132];
  int b = blockIdx.z;
  A += (long)b * sA; Bm += (long)b * sB; Cm += (long)b * sC;
  const float* dvb = GCN ? (dv + (long)b * NN) : nullptr;
  const float* xxb = (EPI == 2) ? (xx + (long)b * NN) : nullptr;
  const float* yyb = (EPI == 2) ? (yy + (long)b * NN) : nullptr;
  int m0 = blockIdx.y * 128, n0 = blockIdx.x * 128;
  int tid = threadIdx.x;
  int tx = tid & 15, ty = tid >> 4;
  float acc[8][8];
#pragma unroll
  for (int i = 0; i < 8; i++)
#pragma unroll
    for (int j = 0; j < 8; j++) acc[i][j] = 0.f;

  float drow = 0.f;
  if (GCN) drow = dvb[m0 + (tid >> 1)];

  for (int k0 = 0; k0 < K; k0 += 8) {
    if (TA == 0) {
      int r = tid >> 1, c4 = (tid & 1) * 4;
      float4 av = *(const float4*)(A + (long)(m0 + r) * K + k0 + c4);
      float a4[4] = {av.x, av.y, av.z, av.w};
      if (GCN) {
#pragma unroll
        for (int q = 0; q < 4; ++q) {
          int gj = k0 + c4 + q;
          float val = a4[q] + ((m0 + r) == gj ? 1.f : 0.f);
          a4[q] = drow * dvb[gj] * val;
        }
      }
      As[c4 + 0][r] = a4[0]; As[c4 + 1][r] = a4[1];
      As[c4 + 2][r] = a4[2]; As[c4 + 3][r] = a4[3];
    } else {
      int kr = tid >> 5, c4 = (tid & 31) * 4;
      float4 av = *(const float4*)(A + (long)(k0 + kr) * M + m0 + c4);
      *(float4*)&As[kr][c4] = av;
    }
    if (TB == 0) {
      int kr = tid >> 5, c4 = (tid & 31) * 4;
      float4 bv = *(const float4*)(Bm + (long)(k0 + kr) * Nn + n0 + c4);
      *(float4*)&Bs[kr][c4] = bv;
    } else {
      int r = tid >> 1, c4 = (tid & 1) * 4;
      float4 bv = *(const float4*)(Bm + (long)(n0 + r) * K + k0 + c4);
      Bs[c4 + 0][r] = bv.x; Bs[c4 + 1][r] = bv.y;
      Bs[c4 + 2][r] = bv.z; Bs[c4 + 3][r] = bv.w;
    }
    __syncthreads();
#pragma unroll
    for (int k = 0; k < 8; ++k) {
      float av[8], bv[8];
      *(float4*)&av[0] = *(const float4*)&As[k][ty * 8];
      *(float4*)&av[4] = *(const float4*)&As[k][ty * 8 + 4];
      *(float4*)&bv[0] = *(const float4*)&Bs[k][tx * 8];
      *(float4*)&bv[4] = *(const float4*)&Bs[k][tx * 8 + 4];
#pragma unroll
      for (int i = 0; i < 8; i++)
#pragma unroll
        for (int j = 0; j < 8; j++)
          acc[i][j] = fmaf(av[i], bv[j], acc[i][j]);
    }
    __syncthreads();
  }
#pragma unroll
  for (int i = 0; i < 8; ++i) {
    int m = m0 + ty * 8 + i;
    float* crow = Cm + (long)m * Nn + n0 + tx * 8;
    float outv[8];
#pragma unroll
    for (int j = 0; j < 8; ++j) {
      float vv = acc[i][j];
      if (EPI == 1) { vv += bias[n0 + tx * 8 + j]; if (relu) vv = fmaxf(vv, 0.f); }
      if (EPI == 2) { vv = xxb[m] + yyb[n0 + tx * 8 + j] - 2.f * vv; }
      outv[j] = vv;
    }
    *(float4*)&crow[0] = *(float4*)&outv[0];
    *(float4*)&crow[4] = *(float4*)&outv[4];
  }
}

// ---------------- column mean over nodes ------------------------------------
__global__ __launch_bounds__(256) void k_colmean(const float* __restrict__ X, int Fd,
                                                 float* __restrict__ out) {
  int nb = Fd >> 6;
  int b = blockIdx.x / nb; int f0 = (blockIdx.x % nb) << 6;
  int t = threadIdx.x;
  int f = f0 + (t & 63); int rc = t >> 6;
  const float* xb = X + (long)b * NN * Fd;
  float s = 0.f;
  for (int i = rc * 256; i < rc * 256 + 256; ++i) s += xb[(long)i * Fd + f];
  __shared__ float sm[256];
  sm[t] = s; __syncthreads();
  if (t < 64) out[b * Fd + f] = (sm[t] + sm[t + 64] + sm[t + 128] + sm[t + 192]) * (1.f / NN);
}

// ---------------- squared row norms -----------------------------------------
__global__ __launch_bounds__(256) void k_sqnorm(const float* __restrict__ X, int Fd,
                                                float* __restrict__ out) {
  int t = threadIdx.x; int lane = t & 63; int wv = t >> 6;
  int row = blockIdx.x * 4 + wv;
  const float* xr = X + (long)row * Fd;
  float s = 0.f;
  for (int f = lane; f < Fd; f += 64) { float v = xr[f]; s = fmaf(v, v, s); }
  s = wred_sum(s);
  if (lane == 0) out[row] = s;
}

// ---------------- Sinkhorn row pass -----------------------------------------
__global__ __launch_bounds__(256) void k_sink_row(const float* __restrict__ Cmat,
                                                  const float* __restrict__ vvec,
                                                  float* __restrict__ uvec) {
  int row = blockIdx.x; int b = row >> 10;
  const float* cr = Cmat + (long)row * NN;
  const float* vb = vvec + (b << 10);
  int t = threadIdx.x;
  float a[4]; float mx = -3.0e38f;
#pragma unroll
  for (int q = 0; q < 4; ++q) {
    int j = (q << 8) + t;
    a[q] = (vb[j] - cr[j]) * INV_EPS;
    mx = fmaxf(mx, a[q]);
  }
  mx = wred_max(mx);
  __shared__ float smm[4], sms[4];
  int lane = t & 63, wv = t >> 6;
  if (lane == 0) smm[wv] = mx;
  __syncthreads();
  float M2 = fmaxf(fmaxf(smm[0], smm[1]), fmaxf(smm[2], smm[3]));
  float s = 0.f;
#pragma unroll
  for (int q = 0; q < 4; ++q) s += __expf(a[q] - M2);
  s = wred_sum(s);
  if (lane == 0) sms[wv] = s;
  __syncthreads();
  if (t == 0) {
    float tot = sms[0] + sms[1] + sms[2] + sms[3];
    uvec[row] = EPS_S * (LOG_MU - (M2 + __logf(tot)));
  }
}

// ---------------- Sinkhorn col pass -----------------------------------------
__global__ __launch_bounds__(256) void k_sink_col(const float* __restrict__ Cmat,
                                                  const float* __restrict__ uvec,
                                                  float* __restrict__ vvec) {
  int b = blockIdx.y;
  int t = threadIdx.x;
  int j = (blockIdx.x << 6) + (t & 63);
  int chunk = t >> 6;
  const float* cb = Cmat + ((long)b << 20);
  const float* ub = uvec + (b << 10);
  float mx = -3.0e38f, s = 0.f;
  int i0 = chunk << 8;
  for (int i = i0; i < i0 + 256; ++i) {
    float av = (ub[i] - cb[((long)i << 10) + j]) * INV_EPS;
    if (av > mx) { s = s * __expf(mx - av) + 1.f; mx = av; }
    else s += __expf(av - mx);
  }
  __shared__ float smm[256], sms[256];
  smm[t] = mx; sms[t] = s;
  __syncthreads();
  if (t < 64) {
    float M2 = smm[t], S2 = sms[t];
#pragma unroll
    for (int c = 1; c < 4; ++c) {
      float mm = smm[t + (c << 6)], ss = sms[t + (c << 6)];
      if (mm > M2) { S2 = S2 * __expf(M2 - mm) + ss; M2 = mm; }
      else S2 += ss * __expf(mm - M2);
    }
    vvec[(b << 10) + j] = EPS_S * (LOG_NU - (M2 + __logf(S2)));
  }
}

// ---------------- loss = sum exp((u+v-C)/eps) * C ---------------------------
__global__ __launch_bounds__(256) void k_loss(const float* __restrict__ Cmat,
                                              const float* __restrict__ u,
                                              const float* __restrict__ v,
                                              float* __restrict__ part) {
  long total = (long)BN * NN * NN;
  float acc = 0.f;
  for (long idx = (long)blockIdx.x * blockDim.x + threadIdx.x; idx < total;
       idx += (long)gridDim.x * blockDim.x) {
    int b = (int)(idx >> 20);
    int i = (int)((idx >> 10) & (NN - 1));
    int j = (int)(idx & (NN - 1));
    float Cv = Cmat[idx];
    float a = (u[(b << 10) + i] + v[(b << 10) + j] - Cv) * INV_EPS;
    acc = fmaf(__expf(a), Cv, acc);
  }
  acc = wred_sum(acc);
  __shared__ float sm[4];
  if ((threadIdx.x & 63) == 0) sm[threadIdx.x >> 6] = acc;
  __syncthreads();
  if (threadIdx.x == 0) part[blockIdx.x] = sm[0] + sm[1] + sm[2] + sm[3];
}

__global__ __launch_bounds__(256) void k_psum(const float* __restrict__ part,
                                              float* __restrict__ out) {
  float s = 0.f;
  for (int i = threadIdx.x; i < LOSS_BLOCKS; i += 256) s += part[i];
  s = wred_sum(s);
  __shared__ float sm[4];
  if ((threadIdx.x & 63) == 0) sm[threadIdx.x >> 6] = s;
  __syncthreads();
  if (threadIdx.x == 0) out[0] = sm[0] + sm[1] + sm[2] + sm[3];
}

extern "C" void kernel_launch(void* const* d_in, const int* in_sizes, int n_in,
                              void* d_out, int out_size, void* d_ws, size_t ws_size,
                              hipStream_t stream) {
  const float* x    = (const float*)d_in[0];
  const float* adj  = (const float*)d_in[1];
  const float* W1   = (const float*)d_in[3];
  const float* b1   = (const float*)d_in[4];
  const float* Watt = (const float*)d_in[5];
  const float* batt = (const float*)d_in[6];
  const float* W2   = (const float*)d_in[7];
  const float* b2   = (const float*)d_in[8];

  float* out = (float*)d_out;
  float* xs0   = out;                    // [8,128]
  float* xs1   = out + 1024;             // [8,256]
  float* oadj0 = out + 3072;             // [8,1024,1024]
  float* oadj1 = oadj0 + 8388608;
  float* oadj2 = oadj1 + 8388608;
  float* oS0   = oadj2 + 8388608;
  float* oS1   = oS0 + 8388608;
  float* oloss = oS1 + 8388608;          // [1]

  float* ws   = (float*)d_ws;
  float* wXW  = ws;                       // 2,097,152
  float* wCXA = wXW + 2097152;            // 1,048,576  (x1, later emb2)
  float* wCXB = wCXA + 1048576;           // 1,048,576  (emb1)
  float* wR   = wCXB + 1048576;           // 8,388,608  (tmp_bf|adj_bf; later C)
  float* wX2  = wR + 8388608;             // 2,097,152  (x2)
  float* wStf = wX2 + 2097152;            // 4,194,304  (St bf16)
  float* wCxtf= wStf + 4194304;           // 524,288    (cxt bf16)
  float* smb  = wCxtf + 524288;
  unsigned short* tmp_bf = (unsigned short*)wR;               // 8.4M bf16
  unsigned short* adj_bf = (unsigned short*)(wR + 4194304);   // 8.4M bf16
  unsigned short* St     = (unsigned short*)wStf;
  unsigned short* cxt    = (unsigned short*)wCxtf;
  float* Cmat = wR;                        // Sinkhorn cost reuses wR
  float* d0 = smb;            float* rm0 = smb + 8192;
  float* d1 = smb + 16384;    float* rm1 = smb + 24576;
  float* d2 = smb + 32768;    float* rm2 = smb + 40960;
  float* s0v = smb + 49152;   float* alp = smb + 57344;
  float* xxv = smb + 65536;   float* yyv = smb + 73728;
  float* uv  = smb + 81920;   float* vv  = smb + 90112;
  float* cutv = smb + 98304;  float* part = smb + 98368;

  // new_adjs[0] = adj
  hipMemcpyAsync(oadj0, adj, (size_t)8388608 * 4, hipMemcpyDeviceToDevice, stream);

  k_rowstats<<<8192, 256, 0, stream>>>(adj, d0, rm0);
  k_f2b<<<8192, 256, 0, stream>>>(adj, adj_bf);

  // ---- first GCN layer (fp32): x1 = relu(norm(adj) @ (x@W1) + b1) ----
  k_gemm<0,0,0,0><<<dim3(1, 64, 1), 256, 0, stream>>>(x, W1, wXW, 8192, HIDN, FIN,
      0L, 0L, 0L, nullptr, nullptr, 0, nullptr, nullptr);
  k_gemm<0,0,1,1><<<dim3(1, 8, 8), 256, 0, stream>>>(adj, wXW, wCXA, 1024, HIDN, 1024,
      1048576L, 131072L, 131072L, d0, b1, 1, nullptr, nullptr);
  k_colmean<<<16, 256, 0, stream>>>(wCXA, HIDN, xs0);

  // ---- coarsen layer 1 ----
  k_rowdot<<<2048, 256, 0, stream>>>(wCXA, Watt, s0v);
  k_alpha<<<8192, 256, 0, stream>>>(adj, d0, s0v, batt, alp);
  k_topk<<<8, 512, 0, stream>>>(alp, cutv);
  k_sbuild<<<8192, 256, 0, stream>>>(adj, d0, rm0, alp, cutv, oS0);
  k_transp<<<dim3(16, 16, 8), 256, 0, stream>>>(oS0, St, 1024, 1024);
  k_transp<<<dim3(2, 16, 8), 256, 0, stream>>>(wCXA, cxt, 1024, 128);
  // emb1 = S^T x1   -> wCXB fp32
  k_mfma_nt<1,0><<<dim3(1, 8, 8), 256, 0, stream>>>(St, cxt, wCXB, nullptr,
      1024, 1024, 1024, 128, 1048576L, 131072L, 131072L);
  // tmp = S^T adj   -> bf16 only
  k_mfma_nt<0,1><<<dim3(8, 8, 8), 256, 0, stream>>>(St, adj_bf, nullptr, tmp_bf,
      1024, 1024, 1024, 1024, 1048576L, 1048576L, 1048576L);
  // adj1 = tmp S    -> fp32 output + bf16 for next layer (overwrites adj_bf)
  k_mfma_nt<1,1><<<dim3(8, 8, 8), 256, 0, stream>>>(tmp_bf, St, oadj1, adj_bf,
      1024, 1024, 1024, 1024, 1048576L, 1048576L, 1048576L);
  k_rowstats<<<8192, 256, 0, stream>>>(oadj1, d1, rm1);

  // ---- coarsen layer 2 ----
  k_rowdot<<<2048, 256, 0, stream>>>(wCXB, Watt, s0v);
  k_alpha<<<8192, 256, 0, stream>>>(oadj1, d1, s0v, batt, alp);
  k_topk<<<8, 512, 0, stream>>>(alp, cutv);
  k_sbuild<<<8192, 256, 0, stream>>>(oadj1, d1, rm1, alp, cutv, oS1);
  k_transp<<<dim3(16, 16, 8), 256, 0, stream>>>(oS1, St, 1024, 1024);
  k_transp<<<dim3(2, 16, 8), 256, 0, stream>>>(wCXB, cxt, 1024, 128);
  // emb2 = S^T emb1 -> wCXA fp32 (x1 dead)
  k_mfma_nt<1,0><<<dim3(1, 8, 8), 256, 0, stream>>>(St, cxt, wCXA, nullptr,
      1024, 1024, 1024, 128, 1048576L, 131072L, 131072L);
  // tmp = S^T adj1
  k_mfma_nt<0,1><<<dim3(8, 8, 8), 256, 0, stream>>>(St, adj_bf, nullptr, tmp_bf,
      1024, 1024, 1024, 1024, 1048576L, 1048576L, 1048576L);
  // adj2 = tmp S    -> fp32 only
  k_mfma_nt<1,0><<<dim3(8, 8, 8), 256, 0, stream>>>(tmp_bf, St, oadj2, nullptr,
      1024, 1024, 1024, 1024, 1048576L, 1048576L, 1048576L);
  k_rowstats<<<8192, 256, 0, stream>>>(oadj2, d2, rm2);

  // ---- final GCN (fp32, feeds Sinkhorn): x2 = norm(adj2) @ (emb2@W2) + b2 ----
  k_gemm<0,0,0,0><<<dim3(2, 64, 1), 256, 0, stream>>>(wCXA, W2, wXW, 8192, FIN, HIDN,
      0L, 0L, 0L, nullptr, nullptr, 0, nullptr, nullptr);
  k_gemm<0,0,1,1><<<dim3(2, 8, 8), 256, 0, stream>>>(oadj2, wXW, wX2, 1024, FIN, 1024,
      1048576L, 262144L, 262144L, d2, b2, 0, nullptr, nullptr);
  k_colmean<<<32, 256, 0, stream>>>(wX2, FIN, xs1);

  // ---- Sinkhorn (fp32) ----
  k_sqnorm<<<2048, 256, 0, stream>>>(x, FIN, xxv);
  k_sqnorm<<<2048, 256, 0, stream>>>(wX2, FIN, yyv);
  k_gemm<0,1,0,2><<<dim3(8, 8, 8), 256, 0, stream>>>(x, wX2, Cmat, 1024, 1024, FIN,
      262144L, 262144L, 1048576L, nullptr, nullptr, 0, xxv, yyv);
  hipMemsetAsync(uv, 0, (size_t)2 * 8192 * 4, stream);
  for (int it = 0; it < NITER; ++it) {
    k_sink_row<<<8192, 256, 0, stream>>>(Cmat, vv, uv);
    k_sink_col<<<dim3(16, 8), 256, 0, stream>>>(Cmat, uv, vv);
  }
  k_loss<<<LOSS_BLOCKS, 256, 0, stream>>>(Cmat, uv, vv, part);
  k_psum<<<1, 256, 0, stream>>>(part, oloss);
}

// Round 3
// 1035.759 us; speedup vs baseline: 3.4954x; 2.5557x over previous
//
#include <hip/hip_runtime.h>
#include <math.h>

// Problem constants (fixed by the reference)
#define BN   8
#define NN   1024
#define FIN  256
#define HIDN 128
#define KTOP 513          // int(1024*0.5)+1
#define NITER 20          // opt_epochs in setup_inputs
#define EPS_S 0.01f
#define INV_EPS 100.0f
#define LOG_MU (-6.9314718055994531f)   // -log(1024)
#define LOSS_BLOCKS 2048

typedef __attribute__((ext_vector_type(8))) short bfrag8;   // 8 bf16 (4 VGPR)
typedef __attribute__((ext_vector_type(4))) float facc4;    // MFMA accumulator

#define GLOAD16(g, l) __builtin_amdgcn_global_load_lds( \
    (const __attribute__((address_space(1))) unsigned int*)(g), \
    (__attribute__((address_space(3))) unsigned int*)(l), 16, 0, 0)

static __device__ __forceinline__ float wred_sum(float s) {
#pragma unroll
  for (int o = 32; o > 0; o >>= 1) s += __shfl_xor(s, o);
  return s;
}
static __device__ __forceinline__ float wred_max(float s) {
#pragma unroll
  for (int o = 32; o > 0; o >>= 1) s = fmaxf(s, __shfl_xor(s, o));
  return s;
}
static __device__ __forceinline__ unsigned short f2b(float f) {
  unsigned int u = __float_as_uint(f);
  u += 0x7fff + ((u >> 16) & 1);      // RNE
  return (unsigned short)(u >> 16);
}

// ---------------- rowsum -> d = rsqrt(max(rowsum+1,1)), rmask = rowsum>0 ----
__global__ __launch_bounds__(256) void k_rowstats(const float* __restrict__ adj,
                                                  float* __restrict__ dv,
                                                  float* __restrict__ rm) {
  int row = blockIdx.x;
  const float* a = adj + (long)row * NN;
  int t = threadIdx.x;
  float4 v = *(const float4*)(a + t * 4);
  float s = v.x + v.y + v.z + v.w;
  s = wred_sum(s);
  __shared__ float sm[4];
  if ((t & 63) == 0) sm[t >> 6] = s;
  __syncthreads();
  if (t == 0) {
    float tot = sm[0] + sm[1] + sm[2] + sm[3];
    dv[row] = rsqrtf(fmaxf(tot + 1.0f, 1.0f));
    rm[row] = tot > 0.0f ? 1.0f : 0.0f;
  }
}

// ---------------- fp32 -> bf16 elementwise ----------------------------------
__global__ __launch_bounds__(256) void k_f2b(const float* __restrict__ X,
                                             unsigned short* __restrict__ Y) {
  long i = ((long)blockIdx.x * 256 + threadIdx.x) * 4;
  float4 v = *(const float4*)(X + i);
  Y[i] = f2b(v.x); Y[i + 1] = f2b(v.y); Y[i + 2] = f2b(v.z); Y[i + 3] = f2b(v.w);
}

// ---------------- fp32 [R][C] -> bf16 [C][R] transpose ----------------------
__global__ __launch_bounds__(256) void k_transp(const float* __restrict__ X,
                                                unsigned short* __restrict__ Xt,
                                                int R, int C) {
  __shared__ float tile[64][65];
  long bb = blockIdx.z;
  const float* Xb = X + bb * (long)R * C;
  unsigned short* Xtb = Xt + bb * (long)R * C;
  int r0 = blockIdx.y * 64, c0 = blockIdx.x * 64;
  int t = threadIdx.x;
  int tr = t >> 4, tc4 = (t & 15) * 4;
#pragma unroll
  for (int p = 0; p < 4; ++p) {
    float4 v = *(const float4*)(Xb + (long)(r0 + tr + p * 16) * C + c0 + tc4);
    tile[tr + p * 16][tc4 + 0] = v.x; tile[tr + p * 16][tc4 + 1] = v.y;
    tile[tr + p * 16][tc4 + 2] = v.z; tile[tr + p * 16][tc4 + 3] = v.w;
  }
  __syncthreads();
  int jj = t >> 2, i0 = (t & 3) * 16;
  unsigned short* orow = Xtb + (long)(c0 + jj) * R + r0 + i0;
#pragma unroll
  for (int q = 0; q < 16; ++q) orow[q] = f2b(tile[i0 + q][jj]);
}

// ---------------- fp32 [NN][NN] -> fp32 [NN][NN] transpose ------------------
__global__ __launch_bounds__(256) void k_transpf(const float* __restrict__ X,
                                                 float* __restrict__ Xt) {
  __shared__ float tile[64][65];
  long bb = blockIdx.z;
  const float* Xb = X + bb * (long)NN * NN;
  float* Xtb = Xt + bb * (long)NN * NN;
  int r0 = blockIdx.y * 64, c0 = blockIdx.x * 64;
  int t = threadIdx.x;
  int tr = t >> 4, tc4 = (t & 15) * 4;
#pragma unroll
  for (int p = 0; p < 4; ++p) {
    float4 v = *(const float4*)(Xb + (long)(r0 + tr + p * 16) * NN + c0 + tc4);
    tile[tr + p * 16][tc4 + 0] = v.x; tile[tr + p * 16][tc4 + 1] = v.y;
    tile[tr + p * 16][tc4 + 2] = v.z; tile[tr + p * 16][tc4 + 3] = v.w;
  }
  __syncthreads();
  int jj = t >> 2, i0 = (t & 3) * 16;
  float* orow = Xtb + (long)(c0 + jj) * NN + r0 + i0;
#pragma unroll
  for (int q = 0; q < 16; q += 4) {
    float4 w4 = { tile[i0 + q][jj], tile[i0 + q + 1][jj],
                  tile[i0 + q + 2][jj], tile[i0 + q + 3][jj] };
    *(float4*)(orow + q) = w4;
  }
}

// ---------------- bf16 NT MFMA GEMM: C[m,n] = sum_k A[m,k]*B[n,k] -----------
template<int WF32, int WBF>
__global__ __launch_bounds__(256) void k_mfma_nt(
    const unsigned short* __restrict__ A, const unsigned short* __restrict__ B,
    float* __restrict__ Cf, unsigned short* __restrict__ Cb,
    int K, int ldA, int ldB, int ldC, long sA, long sB, long sC) {
  __shared__ unsigned short As[128 * 32];
  __shared__ unsigned short Bs[128 * 32];
  int bz = blockIdx.z;
  A += bz * sA; B += bz * sB;
  int m0 = blockIdx.y * 128, n0 = blockIdx.x * 128;
  int tid = threadIdx.x, lane = tid & 63, w = tid >> 6;
  int wr = w >> 1, wc = w & 1;
  facc4 acc[4][4];
#pragma unroll
  for (int i = 0; i < 4; ++i)
#pragma unroll
    for (int j = 0; j < 4; ++j)
#pragma unroll
      for (int q = 0; q < 4; ++q) acc[i][j][q] = 0.f;

  int rA0 = w * 16 + (lane >> 2);   // staging row within 64-row half
  int kslot = lane & 3;             // 16B slot within 64B row

  for (int k0 = 0; k0 < K; k0 += 32) {
#pragma unroll
    for (int i = 0; i < 2; ++i) {
      int row = i * 64 + rA0;
      int ks = (kslot ^ (row & 3)) << 3;   // pre-swizzled global source
      GLOAD16(A + (long)(m0 + row) * ldA + k0 + ks, As + (i * 64 + w * 16) * 32);
      GLOAD16(B + (long)(n0 + row) * ldB + k0 + ks, Bs + (i * 64 + w * 16) * 32);
    }
    __syncthreads();
    bfrag8 af[4], bfr[4];
#pragma unroll
    for (int mi = 0; mi < 4; ++mi) {
      int row = wr * 64 + mi * 16 + (lane & 15);
      int sl = (((lane >> 4) ^ (row & 3)) << 3);   // swizzled read
      af[mi] = *(const bfrag8*)(As + row * 32 + sl);
    }
#pragma unroll
    for (int ni = 0; ni < 4; ++ni) {
      int row = wc * 64 + ni * 16 + (lane & 15);
      int sl = (((lane >> 4) ^ (row & 3)) << 3);
      bfr[ni] = *(const bfrag8*)(Bs + row * 32 + sl);
    }
#pragma unroll
    for (int mi = 0; mi < 4; ++mi)
#pragma unroll
      for (int ni = 0; ni < 4; ++ni)
        acc[mi][ni] = __builtin_amdgcn_mfma_f32_16x16x32_bf16(
            af[mi], bfr[ni], acc[mi][ni], 0, 0, 0);
    __syncthreads();
  }
  if (WF32) Cf += bz * sC;
  if (WBF) Cb += bz * sC;
#pragma unroll
  for (int mi = 0; mi < 4; ++mi) {
    int rowb = m0 + wr * 64 + mi * 16 + ((lane >> 4) << 2);
#pragma unroll
    for (int ni = 0; ni < 4; ++ni) {
      int col = n0 + wc * 64 + ni * 16 + (lane & 15);
#pragma unroll
      for (int q = 0; q < 4; ++q) {
        long off = (long)(rowb + q) * ldC + col;
        float v = acc[mi][ni][q];
        if (WF32) Cf[off] = v;
        if (WBF) Cb[off] = f2b(v);
      }
    }
  }
}

// ---------------- s0 = cx @ Watt  (per-row dot, HID=128) --------------------
__global__ __launch_bounds__(256) void k_rowdot(const float* __restrict__ X,
                                                const float* __restrict__ w,
                                                float* __restrict__ out) {
  int t = threadIdx.x; int lane = t & 63; int wv = t >> 6;
  int row = blockIdx.x * 4 + wv;
  const float* xr = X + (long)row * HIDN;
  float s = xr[lane] * w[lane] + xr[lane + 64] * w[lane + 64];
  s = wred_sum(s);
  if (lane == 0) out[row] = s;
}

// ---------------- alpha = sigmoid((gcn_norm(adj) @ s0 + batt)^2) ------------
__global__ __launch_bounds__(256) void k_alpha(const float* __restrict__ adj,
                                               const float* __restrict__ dv,
                                               const float* __restrict__ s0,
                                               const float* __restrict__ batt,
                                               float* __restrict__ alpha) {
  int row = blockIdx.x; int b = row >> 10; int i = row & (NN - 1);
  const float* a = adj + (long)row * NN;
  const float* db = dv + (b << 10);
  const float* sb = s0 + (b << 10);
  int t = threadIdx.x;
  float s = 0.f;
#pragma unroll
  for (int q = 0; q < 4; ++q) {
    int j = (q << 8) + t;
    float av = a[j] + (j == i ? 1.f : 0.f);
    s += av * db[j] * sb[j];
  }
  s = wred_sum(s);
  __shared__ float sm[4];
  if ((t & 63) == 0) sm[t >> 6] = s;
  __syncthreads();
  if (t == 0) {
    float tt = db[i] * (sm[0] + sm[1] + sm[2] + sm[3]) + batt[0];
    alpha[row] = 1.f / (1.f + __expf(-tt * tt));
  }
}

// ---------------- per-batch k-th largest via bitonic sort -------------------
__global__ __launch_bounds__(512) void k_topk(const float* __restrict__ alpha,
                                              float* __restrict__ cut) {
  __shared__ float smv[NN];
  int b = blockIdx.x; int t = threadIdx.x;
  smv[t] = alpha[(b << 10) + t];
  smv[t + 512] = alpha[(b << 10) + t + 512];
  __syncthreads();
  for (int k2 = 2; k2 <= NN; k2 <<= 1) {
    for (int j2 = k2 >> 1; j2 > 0; j2 >>= 1) {
      int i = ((t / j2) * (j2 << 1)) + (t % j2);
      int ixj = i + j2;
      bool up = ((i & k2) == 0);
      float a = smv[i], c = smv[ixj];
      if ((a > c) == up) { smv[i] = c; smv[ixj] = a; }
      __syncthreads();
    }
  }
  if (t == 0) cut[b] = smv[NN - KTOP];   // ascending sort: 513th largest
}

// ---------------- S build: rmask_i d_i d_j (adj+I) * gate_j, row-L1 norm ----
__global__ __launch_bounds__(256) void k_sbuild(const float* __restrict__ adj,
                                                const float* __restrict__ dv,
                                                const float* __restrict__ rm,
                                                const float* __restrict__ alpha,
                                                const float* __restrict__ cut,
                                                float* __restrict__ S) {
  int row = blockIdx.x; int b = row >> 10; int i = row & (NN - 1);
  const float* a = adj + (long)row * NN;
  const float* db = dv + (b << 10);
  const float* al = alpha + (b << 10);
  float cb = cut[b];
  float di = dv[row] * rm[row];
  int t = threadIdx.x;
  float vals[4]; float s = 0.f;
#pragma unroll
  for (int q = 0; q < 4; ++q) {
    int j = (q << 8) + t;
    float av = a[j] + (j == i ? 1.f : 0.f);
    float gate = fmaxf(al[j] + 1e-7f - cb, 0.f);
    float vv = di * db[j] * av * gate;
    vals[q] = vv; s += fabsf(vv);
  }
  s = wred_sum(s);
  __shared__ float sm[4]; __shared__ float stot;
  if ((t & 63) == 0) sm[t >> 6] = s;
  __syncthreads();
  if (t == 0) stot = 1.f / fmaxf(sm[0] + sm[1] + sm[2] + sm[3], 1e-12f);
  __syncthreads();
  float inv = stot;
  float* Sr = S + (long)row * NN;
#pragma unroll
  for (int q = 0; q < 4; ++q) Sr[(q << 8) + t] = vals[q] * inv;
}

// ---------------- generic fp32 tiled GEMM (plain / Gram epilogue) ----------
template<int TA, int TB, int GCN, int EPI>
__global__ __launch_bounds__(256) void k_gemm(
    const float* __restrict__ A, const float* __restrict__ Bm, float* __restrict__ Cm,
    int M, int Nn, int K, long sA, long sB, long sC,
    const float* __restrict__ dv, const float* __restrict__ bias, int relu,
    const float* __restrict__ xx, const float* __restrict__ yy) {
  __shared__ float As[8][132];
  __shared__ float Bs[8][132];
  int b = blockIdx.z;
  A += (long)b * sA; Bm += (long)b * sB; Cm += (long)b * sC;
  const float* dvb = GCN ? (dv + (long)b * NN) : nullptr;
  const float* xxb = (EPI == 2) ? (xx + (long)b * NN) : nullptr;
  const float* yyb = (EPI == 2) ? (yy + (long)b * NN) : nullptr;
  int m0 = blockIdx.y * 128, n0 = blockIdx.x * 128;
  int tid = threadIdx.x;
  int tx = tid & 15, ty = tid >> 4;
  float acc[8][8];
#pragma unroll
  for (int i = 0; i < 8; i++)
#pragma unroll
    for (int j = 0; j < 8; j++) acc[i][j] = 0.f;

  float drow = 0.f;
  if (GCN) drow = dvb[m0 + (tid >> 1)];

  for (int k0 = 0; k0 < K; k0 += 8) {
    if (TA == 0) {
      int r = tid >> 1, c4 = (tid & 1) * 4;
      float4 av = *(const float4*)(A + (long)(m0 + r) * K + k0 + c4);
      float a4[4] = {av.x, av.y, av.z, av.w};
      if (GCN) {
#pragma unroll
        for (int q = 0; q < 4; ++q) {
          int gj = k0 + c4 + q;
          float val = a4[q] + ((m0 + r) == gj ? 1.f : 0.f);
          a4[q] = drow * dvb[gj] * val;
        }
      }
      As[c4 + 0][r] = a4[0]; As[c4 + 1][r] = a4[1];
      As[c4 + 2][r] = a4[2]; As[c4 + 3][r] = a4[3];
    } else {
      int kr = tid >> 5, c4 = (tid & 31) * 4;
      float4 av = *(const float4*)(A + (long)(k0 + kr) * M + m0 + c4);
      *(float4*)&As[kr][c4] = av;
    }
    if (TB == 0) {
      int kr = tid >> 5, c4 = (tid & 31) * 4;
      float4 bv = *(const float4*)(Bm + (long)(k0 + kr) * Nn + n0 + c4);
      *(float4*)&Bs[kr][c4] = bv;
    } else {
      int r = tid >> 1, c4 = (tid & 1) * 4;
      float4 bv = *(const float4*)(Bm + (long)(n0 + r) * K + k0 + c4);
      Bs[c4 + 0][r] = bv.x; Bs[c4 + 1][r] = bv.y;
      Bs[c4 + 2][r] = bv.z; Bs[c4 + 3][r] = bv.w;
    }
    __syncthreads();
#pragma unroll
    for (int k = 0; k < 8; ++k) {
      float av[8], bv[8];
      *(float4*)&av[0] = *(const float4*)&As[k][ty * 8];
      *(float4*)&av[4] = *(const float4*)&As[k][ty * 8 + 4];
      *(float4*)&bv[0] = *(const float4*)&Bs[k][tx * 8];
      *(float4*)&bv[4] = *(const float4*)&Bs[k][tx * 8 + 4];
#pragma unroll
      for (int i = 0; i < 8; i++)
#pragma unroll
        for (int j = 0; j < 8; j++)
          acc[i][j] = fmaf(av[i], bv[j], acc[i][j]);
    }
    __syncthreads();
  }
#pragma unroll
  for (int i = 0; i < 8; ++i) {
    int m = m0 + ty * 8 + i;
    float* crow = Cm + (long)m * Nn + n0 + tx * 8;
    float outv[8];
#pragma unroll
    for (int j = 0; j < 8; ++j) {
      float vv = acc[i][j];
      if (EPI == 1) { vv += bias[n0 + tx * 8 + j]; if (relu) vv = fmaxf(vv, 0.f); }
      if (EPI == 2) { vv = xxb[m] + yyb[n0 + tx * 8 + j] - 2.f * vv; }
      outv[j] = vv;
    }
    *(float4*)&crow[0] = *(float4*)&outv[0];
    *(float4*)&crow[4] = *(float4*)&outv[4];
  }
}

// ---------------- K-split fp32 GEMM (TA=0,TB=0), partials out ---------------
// z = b*KS + ks; each block computes the k-chunk [ks*KC, (ks+1)*KC) and writes
// its 128x128 tile into P[z][M][Nn].
template<int GCN>
__global__ __launch_bounds__(256) void k_gemm_ks(
    const float* __restrict__ A, const float* __restrict__ Bm, float* __restrict__ P,
    int M, int Nn, int K, int KS, long sA, long sB,
    const float* __restrict__ dv) {
  __shared__ float As[8][132];
  __shared__ float Bs[8][132];
  int z = blockIdx.z;
  int b = z / KS, ks = z % KS;
  int KC = K / KS;
  A += (long)b * sA; Bm += (long)b * sB;
  const float* dvb = GCN ? (dv + (long)b * NN) : nullptr;
  int m0 = blockIdx.y * 128, n0 = blockIdx.x * 128;
  int tid = threadIdx.x;
  int tx = tid & 15, ty = tid >> 4;
  float acc[8][8];
#pragma unroll
  for (int i = 0; i < 8; i++)
#pragma unroll
    for (int j = 0; j < 8; j++) acc[i][j] = 0.f;

  float drow = 0.f;
  if (GCN) drow = dvb[m0 + (tid >> 1)];

  for (int k0 = ks * KC; k0 < ks * KC + KC; k0 += 8) {
    {
      int r = tid >> 1, c4 = (tid & 1) * 4;
      float4 av = *(const float4*)(A + (long)(m0 + r) * K + k0 + c4);
      float a4[4] = {av.x, av.y, av.z, av.w};
      if (GCN) {
#pragma unroll
        for (int q = 0; q < 4; ++q) {
          int gj = k0 + c4 + q;
          float val = a4[q] + ((m0 + r) == gj ? 1.f : 0.f);
          a4[q] = drow * dvb[gj] * val;
        }
      }
      As[c4 + 0][r] = a4[0]; As[c4 + 1][r] = a4[1];
      As[c4 + 2][r] = a4[2]; As[c4 + 3][r] = a4[3];
    }
    {
      int kr = tid >> 5, c4 = (tid & 31) * 4;
      float4 bv = *(const float4*)(Bm + (long)(k0 + kr) * Nn + n0 + c4);
      *(float4*)&Bs[kr][c4] = bv;
    }
    __syncthreads();
#pragma unroll
    for (int k = 0; k < 8; ++k) {
      float av[8], bv[8];
      *(float4*)&av[0] = *(const float4*)&As[k][ty * 8];
      *(float4*)&av[4] = *(const float4*)&As[k][ty * 8 + 4];
      *(float4*)&bv[0] = *(const float4*)&Bs[k][tx * 8];
      *(float4*)&bv[4] = *(const float4*)&Bs[k][tx * 8 + 4];
#pragma unroll
      for (int i = 0; i < 8; i++)
#pragma unroll
        for (int j = 0; j < 8; j++)
          acc[i][j] = fmaf(av[i], bv[j], acc[i][j]);
    }
    __syncthreads();
  }
  float* Pz = P + (long)z * M * Nn;
#pragma unroll
  for (int i = 0; i < 8; ++i) {
    int m = m0 + ty * 8 + i;
    float* prow = Pz + (long)m * Nn + n0 + tx * 8;
    *(float4*)&prow[0] = *(float4*)&acc[i][0];
    *(float4*)&prow[4] = *(float4*)&acc[i][4];
  }
}

// ---------------- reduce K-split partials (+bias, +relu) --------------------
template<int RELU, int BIAS>
__global__ __launch_bounds__(256) void k_red_bias(
    const float* __restrict__ P, const float* __restrict__ bias,
    float* __restrict__ out, int Nn, int KS, long chunk) {
  long u = ((long)blockIdx.x * 256 + threadIdx.x) * 4;
  long b = u / chunk; long rem = u % chunk;
  const float* p = P + b * KS * chunk + rem;
  float4 s = *(const float4*)p;
  for (int k = 1; k < KS; ++k) {
    float4 q = *(const float4*)(p + (long)k * chunk);
    s.x += q.x; s.y += q.y; s.z += q.z; s.w += q.w;
  }
  if (BIAS) {
    int n = (int)(rem % Nn);
    s.x += bias[n]; s.y += bias[n + 1]; s.z += bias[n + 2]; s.w += bias[n + 3];
  }
  if (RELU) {
    s.x = fmaxf(s.x, 0.f); s.y = fmaxf(s.y, 0.f);
    s.z = fmaxf(s.z, 0.f); s.w = fmaxf(s.w, 0.f);
  }
  *(float4*)(out + u) = s;
}

// ---------------- column mean over nodes ------------------------------------
__global__ __launch_bounds__(256) void k_colmean(const float* __restrict__ X, int Fd,
                                                 float* __restrict__ out) {
  int nb = Fd >> 6;
  int b = blockIdx.x / nb; int f0 = (blockIdx.x % nb) << 6;
  int t = threadIdx.x;
  int f = f0 + (t & 63); int rc = t >> 6;
  const float* xb = X + (long)b * NN * Fd;
  float s = 0.f;
  for (int i = rc * 256; i < rc * 256 + 256; ++i) s += xb[(long)i * Fd + f];
  __shared__ float sm[256];
  sm[t] = s; __syncthreads();
  if (t < 64) out[b * Fd + f] = (sm[t] + sm[t + 64] + sm[t + 128] + sm[t + 192]) * (1.f / NN);
}

// ---------------- squared row norms -----------------------------------------
__global__ __launch_bounds__(256) void k_sqnorm(const float* __restrict__ X, int Fd,
                                                float* __restrict__ out) {
  int t = threadIdx.x; int lane = t & 63; int wv = t >> 6;
  int row = blockIdx.x * 4 + wv;
  const float* xr = X + (long)row * Fd;
  float s = 0.f;
  for (int f = lane; f < Fd; f += 64) { float v = xr[f]; s = fmaf(v, v, s); }
  s = wred_sum(s);
  if (lane == 0) out[row] = s;
}

// ---------------- Sinkhorn pass: out_i = eps*(logk - LSE_j((in_j-M_ij)/eps))
// Works for both half-iterations: row pass on C, col pass on C^T.
__global__ __launch_bounds__(256) void k_sink_pass(const float* __restrict__ Mb,
                                                   const float* __restrict__ vin,
                                                   float* __restrict__ uout) {
  int row = blockIdx.x; int b = row >> 10;
  const float4* cr = (const float4*)(Mb + (long)row * NN);
  const float4* vb = (const float4*)(vin + (b << 10));
  int t = threadIdx.x;
  float4 c4 = cr[t], v4 = vb[t];
  float a0 = (v4.x - c4.x) * INV_EPS, a1 = (v4.y - c4.y) * INV_EPS;
  float a2 = (v4.z - c4.z) * INV_EPS, a3 = (v4.w - c4.w) * INV_EPS;
  float mx = fmaxf(fmaxf(a0, a1), fmaxf(a2, a3));
  mx = wred_max(mx);
  __shared__ float smm[4], sms[4];
  int lane = t & 63, wv = t >> 6;
  if (lane == 0) smm[wv] = mx;
  __syncthreads();
  float M2 = fmaxf(fmaxf(smm[0], smm[1]), fmaxf(smm[2], smm[3]));
  float s = __expf(a0 - M2) + __expf(a1 - M2) + __expf(a2 - M2) + __expf(a3 - M2);
  s = wred_sum(s);
  if (lane == 0) sms[wv] = s;
  __syncthreads();
  if (t == 0) {
    float tot = sms[0] + sms[1] + sms[2] + sms[3];
    uout[row] = EPS_S * (LOG_MU - (M2 + __logf(tot)));
  }
}

// ---------------- loss = sum exp((u+v-C)/eps) * C ---------------------------
__global__ __launch_bounds__(256) void k_loss(const float* __restrict__ Cmat,
                                              const float* __restrict__ u,
                                              const float* __restrict__ v,
                                              float* __restrict__ part) {
  long total = (long)BN * NN * NN;
  float acc = 0.f;
  for (long idx = (long)blockIdx.x * blockDim.x + threadIdx.x; idx < total;
       idx += (long)gridDim.x * blockDim.x) {
    int b = (int)(idx >> 20);
    int i = (int)((idx >> 10) & (NN - 1));
    int j = (int)(idx & (NN - 1));
    float Cv = Cmat[idx];
    float a = (u[(b << 10) + i] + v[(b << 10) + j] - Cv) * INV_EPS;
    acc = fmaf(__expf(a), Cv, acc);
  }
  acc = wred_sum(acc);
  __shared__ float sm[4];
  if ((threadIdx.x & 63) == 0) sm[threadIdx.x >> 6] = acc;
  __syncthreads();
  if (threadIdx.x == 0) part[blockIdx.x] = sm[0] + sm[1] + sm[2] + sm[3];
}

__global__ __launch_bounds__(256) void k_psum(const float* __restrict__ part,
                                              float* __restrict__ out) {
  float s = 0.f;
  for (int i = threadIdx.x; i < LOSS_BLOCKS; i += 256) s += part[i];
  s = wred_sum(s);
  __shared__ float sm[4];
  if ((threadIdx.x & 63) == 0) sm[threadIdx.x >> 6] = s;
  __syncthreads();
  if (threadIdx.x == 0) out[0] = sm[0] + sm[1] + sm[2] + sm[3];
}

extern "C" void kernel_launch(void* const* d_in, const int* in_sizes, int n_in,
                              void* d_out, int out_size, void* d_ws, size_t ws_size,
                              hipStream_t stream) {
  const float* x    = (const float*)d_in[0];
  const float* adj  = (const float*)d_in[1];
  const float* W1   = (const float*)d_in[3];
  const float* b1   = (const float*)d_in[4];
  const float* Watt = (const float*)d_in[5];
  const float* batt = (const float*)d_in[6];
  const float* W2   = (const float*)d_in[7];
  const float* b2   = (const float*)d_in[8];

  float* out = (float*)d_out;
  float* xs0   = out;                    // [8,128]
  float* xs1   = out + 1024;             // [8,256]
  float* oadj0 = out + 3072;             // [8,1024,1024] — used as Ct scratch
  float* oadj1 = oadj0 + 8388608;
  float* oadj2 = oadj1 + 8388608;
  float* oS0   = oadj2 + 8388608;
  float* oS1   = oS0 + 8388608;
  float* oloss = oS1 + 8388608;          // [1]

  float* ws   = (float*)d_ws;
  float* wXW  = ws;                       // 2,097,152
  float* wCXA = wXW + 2097152;            // 1,048,576  (x1, later emb2)
  float* wCXB = wCXA + 1048576;           // 1,048,576  (emb1)
  float* wR   = wCXB + 1048576;           // 8,388,608  (K-split partials | bf16 | Cmat)
  float* wX2  = wR + 8388608;             // 2,097,152  (x2)
  float* wStf = wX2 + 2097152;            // 4,194,304  (St bf16)
  float* wCxtf= wStf + 4194304;           // 524,288    (cxt bf16)
  float* smb  = wCxtf + 524288;
  unsigned short* tmp_bf = (unsigned short*)wR;               // 8.4M bf16
  unsigned short* adj_bf = (unsigned short*)(wR + 4194304);   // 8.4M bf16
  unsigned short* St     = (unsigned short*)wStf;
  unsigned short* cxt    = (unsigned short*)wCxtf;
  float* Cmat = wR;                        // Sinkhorn cost reuses wR
  float* Ct   = oadj0;                     // C^T lives in oadj0 until the end
  float* d0 = smb;            float* rm0 = smb + 8192;
  float* d1 = smb + 16384;    float* rm1 = smb + 24576;
  float* d2 = smb + 32768;    float* rm2 = smb + 40960;
  float* s0v = smb + 49152;   float* alp = smb + 57344;
  float* xxv = smb + 65536;   float* yyv = smb + 73728;
  float* uv  = smb + 81920;   float* vv  = smb + 90112;
  float* cutv = smb + 98304;  float* part = smb + 98368;

  k_rowstats<<<8192, 256, 0, stream>>>(adj, d0, rm0);

  // ---- first GCN layer (fp32, K-split): x1 = relu(norm(adj)@(x@W1) + b1) ----
  // xW1: M=8192,N=128,K=256, split 2 -> partials in wR, reduce into wXW
  k_gemm_ks<0><<<dim3(1, 64, 2), 256, 0, stream>>>(x, W1, wR, 8192, HIDN, FIN, 2,
      0L, 0L, nullptr);
  k_red_bias<0,0><<<1024, 256, 0, stream>>>(wR, nullptr, wXW, HIDN, 2, 1048576L);
  // adj GCN: split 8 -> 512 blocks; partials exactly fill wR
  k_gemm_ks<1><<<dim3(1, 8, 64), 256, 0, stream>>>(adj, wXW, wR, 1024, HIDN, 1024, 8,
      1048576L, 131072L, d0);
  k_red_bias<1,1><<<1024, 256, 0, stream>>>(wR, b1, wCXA, HIDN, 8, 131072L);
  k_colmean<<<16, 256, 0, stream>>>(wCXA, HIDN, xs0);

  k_f2b<<<8192, 256, 0, stream>>>(adj, adj_bf);   // after wR partials are dead

  // ---- coarsen layer 1 ----
  k_rowdot<<<2048, 256, 0, stream>>>(wCXA, Watt, s0v);
  k_alpha<<<8192, 256, 0, stream>>>(adj, d0, s0v, batt, alp);
  k_topk<<<8, 512, 0, stream>>>(alp, cutv);
  k_sbuild<<<8192, 256, 0, stream>>>(adj, d0, rm0, alp, cutv, oS0);
  k_transp<<<dim3(16, 16, 8), 256, 0, stream>>>(oS0, St, 1024, 1024);
  k_transp<<<dim3(2, 16, 8), 256, 0, stream>>>(wCXA, cxt, 1024, 128);
  k_mfma_nt<1,0><<<dim3(1, 8, 8), 256, 0, stream>>>(St, cxt, wCXB, nullptr,
      1024, 1024, 1024, 128, 1048576L, 131072L, 131072L);
  k_mfma_nt<0,1><<<dim3(8, 8, 8), 256, 0, stream>>>(St, adj_bf, nullptr, tmp_bf,
      1024, 1024, 1024, 1024, 1048576L, 1048576L, 1048576L);
  k_mfma_nt<1,1><<<dim3(8, 8, 8), 256, 0, stream>>>(tmp_bf, St, oadj1, adj_bf,
      1024, 1024, 1024, 1024, 1048576L, 1048576L, 1048576L);
  k_rowstats<<<8192, 256, 0, stream>>>(oadj1, d1, rm1);

  // ---- coarsen layer 2 ----
  k_rowdot<<<2048, 256, 0, stream>>>(wCXB, Watt, s0v);
  k_alpha<<<8192, 256, 0, stream>>>(oadj1, d1, s0v, batt, alp);
  k_topk<<<8, 512, 0, stream>>>(alp, cutv);
  k_sbuild<<<8192, 256, 0, stream>>>(oadj1, d1, rm1, alp, cutv, oS1);
  k_transp<<<dim3(16, 16, 8), 256, 0, stream>>>(oS1, St, 1024, 1024);
  k_transp<<<dim3(2, 16, 8), 256, 0, stream>>>(wCXB, cxt, 1024, 128);
  k_mfma_nt<1,0><<<dim3(1, 8, 8), 256, 0, stream>>>(St, cxt, wCXA, nullptr,
      1024, 1024, 1024, 128, 1048576L, 131072L, 131072L);
  k_mfma_nt<0,1><<<dim3(8, 8, 8), 256, 0, stream>>>(St, adj_bf, nullptr, tmp_bf,
      1024, 1024, 1024, 1024, 1048576L, 1048576L, 1048576L);
  k_mfma_nt<1,0><<<dim3(8, 8, 8), 256, 0, stream>>>(tmp_bf, St, oadj2, nullptr,
      1024, 1024, 1024, 1024, 1048576L, 1048576L, 1048576L);
  k_rowstats<<<8192, 256, 0, stream>>>(oadj2, d2, rm2);

  // ---- final GCN (fp32, K-split): x2 = norm(adj2)@(emb2@W2) + b2 ----
  k_gemm<0,0,0,0><<<dim3(2, 64, 1), 256, 0, stream>>>(wCXA, W2, wXW, 8192, FIN, HIDN,
      0L, 0L, 0L, nullptr, nullptr, 0, nullptr, nullptr);
  k_gemm_ks<1><<<dim3(2, 8, 32), 256, 0, stream>>>(oadj2, wXW, wR, 1024, FIN, 1024, 4,
      1048576L, 262144L, d2);
  k_red_bias<0,1><<<2048, 256, 0, stream>>>(wR, b2, wX2, FIN, 4, 262144L);
  k_colmean<<<32, 256, 0, stream>>>(wX2, FIN, xs1);

  // ---- Sinkhorn (fp32): C in wR, C^T in oadj0 scratch ----
  k_sqnorm<<<2048, 256, 0, stream>>>(x, FIN, xxv);
  k_sqnorm<<<2048, 256, 0, stream>>>(wX2, FIN, yyv);
  k_gemm<0,1,0,2><<<dim3(8, 8, 8), 256, 0, stream>>>(x, wX2, Cmat, 1024, 1024, FIN,
      262144L, 262144L, 1048576L, nullptr, nullptr, 0, xxv, yyv);
  k_transpf<<<dim3(16, 16, 8), 256, 0, stream>>>(Cmat, Ct);
  hipMemsetAsync(uv, 0, (size_t)2 * 8192 * 4, stream);
  for (int it = 0; it < NITER; ++it) {
    k_sink_pass<<<8192, 256, 0, stream>>>(Cmat, vv, uv);   // u update (rows of C)
    k_sink_pass<<<8192, 256, 0, stream>>>(Ct, uv, vv);     // v update (rows of C^T)
  }
  k_loss<<<LOSS_BLOCKS, 256, 0, stream>>>(Cmat, uv, vv, part);
  k_psum<<<1, 256, 0, stream>>>(part, oloss);

  // new_adjs[0] = adj (after Ct scratch in oadj0 is dead)
  hipMemcpyAsync(oadj0, adj, (size_t)8388608 * 4, hipMemcpyDeviceToDevice, stream);
}